// Round 6
// baseline (228.322 us; speedup 1.0000x reference)
//
#include <hip/hip_runtime.h>
#include <math.h>

#define NN   5000
#define DEG  16
#define S    17
#define T    10
#define MN   10
#define D    128
#define NOUT 3
#define NSK  5

#define WPB   8            // waves per block (wave-private work; no barrier)
#define BLOCK (WPB * 64)
#define NEG   -3.0e38f
#define LOG2E 1.44269504088896f
#define LN2   0.69314718055995f
#define TINY  1e-30f       // cs floor: keeps inactive-column v_ finite (0*inf=NaN!)

typedef unsigned uint2v __attribute__((ext_vector_type(2)));

__device__ __forceinline__ float fast_rcp(float x) { return __builtin_amdgcn_rcpf(x); }

#if __has_builtin(__builtin_amdgcn_exp2f)
__device__ __forceinline__ float fast_exp2(float x) { return __builtin_amdgcn_exp2f(x); }
#else
__device__ __forceinline__ float fast_exp2(float x) { return __expf(x * LN2); }
#endif

// DPP row_ror:k — pure-VALU cross-lane within each 16-lane row. The mov+op
// pairs are fused to v_add_f32_dpp/v_max_f32_dpp by GCNDPPCombine
// (bound_ctrl=1), so each stage is one VALU inst.
template <int CTRL>
__device__ __forceinline__ float dpp_movf(float v) {
    return __int_as_float(__builtin_amdgcn_update_dpp(
        0, __float_as_int(v), CTRL, 0xF, 0xF, true));
}
__device__ __forceinline__ float rowsum16(float v) {
    v += dpp_movf<0x121>(v);
    v += dpp_movf<0x122>(v);
    v += dpp_movf<0x124>(v);
    v += dpp_movf<0x128>(v);
    return v;
}
__device__ __forceinline__ float rowmax16(float v) {
    v = fmaxf(v, dpp_movf<0x121>(v));
    v = fmaxf(v, dpp_movf<0x122>(v));
    v = fmaxf(v, dpp_movf<0x124>(v));
    v = fmaxf(v, dpp_movf<0x128>(v));
    return v;
}

// gfx950 permlane-swap butterflies: v + v[lane^16] / v[lane^32] in pure VALU.
__device__ __forceinline__ float bfly16(float v) {
#if __has_builtin(__builtin_amdgcn_permlane16_swap)
    uint2v r = __builtin_amdgcn_permlane16_swap(__float_as_uint(v), __float_as_uint(v),
                                                false, false);
    return __uint_as_float(r[0]) + __uint_as_float(r[1]);
#else
    return v + __int_as_float(__builtin_amdgcn_ds_swizzle(__float_as_int(v), 0x401F));
#endif
}
__device__ __forceinline__ float bfly32(float v) {
#if __has_builtin(__builtin_amdgcn_permlane32_swap)
    uint2v r = __builtin_amdgcn_permlane32_swap(__float_as_uint(v), __float_as_uint(v),
                                                false, false);
    return __uint_as_float(r[0]) + __uint_as_float(r[1]);
#else
    return v + __shfl_xor(v, 32, 64);
#endif
}

// 10-term dot of an LDS row (16B-aligned, 16-float stride) with a register
// array: 3 vector ds_reads (LDS pipe, co-issues with VALU) + 14 VALU, tree
// depth ~3.
__device__ __forceinline__ float dot10(const float* __restrict__ row,
                                       const float* __restrict__ cr) {
    float4 a = *(const float4*)(row);
    float4 b = *(const float4*)(row + 4);
    float2 c = *(const float2*)(row + 8);
    float e0 = fmaf(cr[1], a.y, cr[0] * a.x);
    float e1 = fmaf(cr[3], a.w, cr[2] * a.z);
    float e2 = fmaf(cr[5], b.y, cr[4] * b.x);
    float e3 = fmaf(cr[7], b.w, cr[6] * b.z);
    float e4 = fmaf(cr[9], c.y, cr[8] * c.x);
    return ((e0 + e1) + (e2 + e3)) + e4;
}

// ---------------- Pre-kernel: batch the per-node redundant work ----------------
// (unchanged) Mp[n,c] = xsq[n] - 2*(x[n].F2f[c]); masks[n][s]; sqF2[100].
__global__ __launch_bounds__(320) void ltfgw_pre(
    const float* __restrict__ x,        // [N, D]
    const int*   __restrict__ edge,     // [2, N*DEG]
    const float* __restrict__ F2,       // [T, MN, D] == [100, D] flat
    float*       __restrict__ wsMp,     // [N, 100]  xsq[n] - 2*dot
    unsigned*    __restrict__ wsMask,   // [N, 17]   adjacency bitmasks
    float*       __restrict__ wsSqF2)   // [100]
{
    const int n   = blockIdx.x;
    const int tid = threadIdx.x;
    const int* dst = edge + NN * DEG;

    if (n == NN) {                       // sqF2[c] = ||F2f[c]||^2
        if (tid < T * MN) {
            const float4* fr = (const float4*)(F2 + (size_t)tid * D);
            float acc = 0.f;
            #pragma unroll 8
            for (int i = 0; i < D / 4; ++i) {
                float4 f = fr[i];
                acc += f.x*f.x + f.y*f.y + f.z*f.z + f.w*f.w;
            }
            wsSqF2[tid] = acc;
        }
        return;
    }

    __shared__ int      loc[S];
    __shared__ int      neigh[S][DEG];
    __shared__ unsigned cm[S];
    __shared__ float    xsq_s;

    if (tid < S) { loc[tid] = (tid == 0) ? n : dst[n * DEG + tid - 1]; cm[tid] = 0u; }
    __syncthreads();

    if (tid < S * DEG) neigh[tid >> 4][tid & 15] = dst[loc[tid >> 4] * DEG + (tid & 15)];
    if (tid < 64) {                      // xsq[n] via wave-0 DPP reduce
        float v0 = x[(size_t)n * D + tid];
        float v1 = x[(size_t)n * D + 64 + tid];
        float pp = v0 * v0 + v1 * v1;
        pp = rowsum16(pp);
        pp += __shfl_xor(pp, 16, 64);
        pp += __shfl_xor(pp, 32, 64);
        if (tid == 0) xsq_s = pp;
    }
    __syncthreads();

    if (tid < S * S) {
        int a = tid / S, b = tid % S;
        int la = loc[a], lb = loc[b];
        bool adj = false;
        #pragma unroll
        for (int k = 0; k < DEG; ++k) adj = adj | (neigh[a][k] == lb) | (neigh[b][k] == la);
        if (a != b && adj) atomicOr(&cm[a], 1u << b);
    }
    __syncthreads();

    if (tid < S) wsMask[n * S + tid] = cm[tid];
    if (tid >= 32 && tid < 32 + T * MN) {  // Mp[n,c] = xsq - 2*(x[n].F2f[c])
        int c = tid - 32;
        const float4* fr = (const float4*)(F2 + (size_t)c * D);
        const float4* xr = (const float4*)(x + (size_t)n * D);
        float dotv = 0.f;
        #pragma unroll 8
        for (int d4 = 0; d4 < D / 4; ++d4) {
            float4 f = fr[d4], xv = xr[d4];
            dotv += f.x*xv.x + f.y*xv.y + f.z*xv.z + f.w*xv.w;
        }
        wsMp[n * (T * MN) + c] = xsq_s - 2.f * dotv;
    }
}

// ---------------- Main: one wave = one (node, template) OT problem ----------------
// Round-14: issue-count + branch-bubble trims on the R13 structure (real VALU
// issue util ~48%: latency-bound at the HW occupancy cap of 8 waves/SIMD).
//  (a) act-mask hoisted into lkP2b (=NEG on inactive lanes, prologue): removes
//      15 cndmask from the per-outer exp2 chain; exp2(NEG+bounded)=0 exactly.
//  (b) G[r] = aR[r]*pv where aR = last sink iteration's Kt*ub products (saved
//      from the cs tree). a4 uses gated Kt4c so G[4]==0 on q>0 quads, which
//      also deletes the (q==0) gate on colG.
//  (c) extras processed via ONE union-mask loop (per popped bit: dot10 + 5
//      gated adds) instead of 5 per-r while-loops: 1 branch region per outer.
//  (d) TINY kept in the cs tree (NOT on the a4 product) so (b) stays exact.
// __launch_bounds__: block size ONLY (rounds 2-3: min-waves hint => spills).
__global__ __launch_bounds__(BLOCK) void ltfgw_wave(
    const int*      __restrict__ edge,     // [2, N*DEG]
    const float*    __restrict__ tmpl,     // [T, MN, MN]
    const float*    __restrict__ q0,       // [T, MN]
    const float*    __restrict__ alpha0,   // [1]
    const float*    __restrict__ wsMp,     // [N, 100]
    const unsigned* __restrict__ wsMask,   // [N, 17]
    const float*    __restrict__ wsSqF2,   // [100]
    float*          __restrict__ out)      // [N, T]
{
    const int tid  = threadIdx.x;
    const int w    = tid >> 6;
    const int gid  = blockIdx.x * WPB + w;   // flat (node, template) id
    const int n    = gid / T;
    const int t    = gid - n * T;
    const int lane = tid & 63;
    const int q    = lane >> 4;
    const int m    = lane & 15;
    const bool act = (m < MN);
    const int mc   = act ? m : (MN - 1);

    __shared__ __align__(16) float C2l[WPB][MN][17]; // wave-private; stride 17
    __shared__ __align__(16) float GL[WPB][19][16];  // rows 0-16: G; 17: colG; 18: dump
    __shared__ __align__(16) float QL[WPB][16];      // q-weights (tail zeroed)

    const int* dst = edge + NN * DEG;

    // q = softmax(q0[t]) via DPP row reduction (all lanes)
    float vq = q0[t * MN + mc];
    float zq = act ? vq : NEG;
    float mq = rowmax16(zq);
    float sq = rowsum16(__expf(zq - mq));     // inactive: exp(NEG-mq)=0
    const float qm = __expf(vq - (mq + __logf(sq)));   // valid on act lanes
    if (q == 0) QL[w][m] = act ? qm : 0.f;    // q vector to LDS (tail = 0)
    // C2 = softmax(tmpl, axis=1): active lane m of quad 0 does column m
    if (act && q == 0) {
        float v[MN]; float cmx = NEG;
        #pragma unroll
        for (int i = 0; i < MN; ++i) { v[i] = tmpl[t * MN * MN + i * MN + m]; cmx = fmaxf(cmx, v[i]); }
        float ssum = 0.f;
        #pragma unroll
        for (int i = 0; i < MN; ++i) { v[i] = __expf(v[i] - cmx); ssum += v[i]; }
        float inv = fast_rcp(ssum);
        #pragma unroll
        for (int i = 0; i < MN; ++i) C2l[w][i][m] = v[i] * inv;
    }

    // per-row gathers (L1/L2-resident ws): rows sr[r] = q+4r, clamp 16
    int sr[5];
    #pragma unroll
    for (int r = 0; r < 5; ++r) { int s0 = q + 4 * r; sr[r] = (s0 > 16) ? 16 : s0; }
    unsigned msk[5]; float npop[5]; float Mp[5];
    const int cidx = t * MN + mc;
    #pragma unroll
    for (int r = 0; r < 5; ++r) {
        int lr  = (sr[r] == 0) ? n : dst[n * DEG + sr[r] - 1];
        msk[r]  = wsMask[n * S + sr[r]];
        npop[r] = (float)__popc(msk[r]);
        Mp[r]   = wsMp[lr * (T * MN) + cidx];
    }
    const float sqf2c = wsSqF2[cidx];

    // C2 row mc in registers (stride-17 b32 reads: 10 distinct banks, no
    // conflict; same-wave LDS RAW ordered by compiler lgkmcnt)
    float crReg[MN];
    #pragma unroll
    for (int k = 0; k < MN; ++k) crReg[k] = C2l[w][mc][k];

    // hC2 = sum_k C2[mc][k]^2 q[k]; qC2m = sum_k C2[mc][k] q[k]
    float hC2 = 0.f, qC2m = 0.f;
    {
        float ql[MN];
        #pragma unroll
        for (int k = 0; k < MN; ++k) ql[k] = QL[w][k];
        #pragma unroll
        for (int k = 0; k < MN; ++k) {
            float cq = crReg[k] * ql[k];
            qC2m += cq;
            hC2  = fmaf(crReg[k], cq, hC2);
        }
    }

    const float alpha = fast_rcp(1.f + __expf(-alpha0[0]));
    const float oma   = 1.f - alpha;
    const float p_    = 1.f / (float)S;
    const float fa42  = 40.f * alpha * LOG2E; // log2K = lkP2 + fa42*tens
    const float qop   = qm * (float)S;        // q/p for folded v-update
    const unsigned exm = act ? 0x1FFFEu : 0u; // extras mask (skip bit 0; gate act)
    const int j16  = (q == 0) ? 16 : 18;      // row-16 G write: q>0 -> dump row

    // lkP2b = log2-domain linear part, pre-shifted by hoisted row stabilizer.
    // Inactive lanes get NEG => Kt = exp2(NEG + bounded) = 0 with no per-outer
    // cndmask (act-mask hoist).
    float lkP2b[5], rm2[5];
    {
        const float nl2e10 = -10.f * LOG2E;
        #pragma unroll
        for (int r = 0; r < 5; ++r) {
            float M_ = Mp[r] + sqf2c;             // xsq + sqf2 - 2*dot
            float cC = npop[r] * p_ + hC2;        // hC1 = popc/S
            float lk2 = nl2e10 * (oma * M_ + 2.f * alpha * cC);
            rm2[r]   = rowmax16(act ? lk2 : NEG) + 14.4f;  // overflow headroom
            lkP2b[r] = act ? (lk2 - rm2[r]) : NEG;
        }
    }

    // outer 0 analytic: G0 = p q^T => tens0[r] = p * qC2m * popc(msk[r])
    float tens[5], Kt[5], ub[5], aR[5], v_, G[5];
    {
        float pq = p_ * qC2m;
        #pragma unroll
        for (int r = 0; r < 5; ++r) tens[r] = pq * npop[r];
    }

    for (int o = 1; o <= NOUT; ++o) {
        // K~ = exp2(lkP2b + fa42*tens)  (rowmax hoisted; Sinkhorn scale-invariant)
        #pragma unroll
        for (int r = 0; r < 5; ++r)
            Kt[r] = fast_exp2(fmaf(fa42, tens[r], lkP2b[r]));
        float Kt4c = (q == 0) ? Kt[4] : 0.f;   // row 16 counted once in cs

        // folded exp-domain Sinkhorn: û = rcp(K~ v); v = (Sq)*rcp(K~^T û)
        // iter 0 peeled (v == 1). cs floored by TINY so inactive columns
        // (all-Kt==0) give finite v_; Kt*v_ stays exactly 0 there.
        #pragma unroll
        for (int r = 0; r < 5; ++r) ub[r] = fast_rcp(rowsum16(Kt[r]));
        {
            aR[0] = Kt[0] * ub[0]; aR[1] = Kt[1] * ub[1];
            aR[2] = Kt[2] * ub[2]; aR[3] = Kt[3] * ub[3];
            aR[4] = Kt4c * ub[4];
            float cs = ((aR[0] + aR[1]) + (aR[2] + aR[3])) + (aR[4] + TINY);
            cs = bfly16(cs); cs = bfly32(cs);
            v_ = qop * fast_rcp(cs);
        }
        #pragma unroll
        for (int it = 1; it < NSK; ++it) {
            #pragma unroll
            for (int r = 0; r < 5; ++r)
                ub[r] = fast_rcp(rowsum16(Kt[r] * v_));
            aR[0] = Kt[0] * ub[0]; aR[1] = Kt[1] * ub[1];
            aR[2] = Kt[2] * ub[2]; aR[3] = Kt[3] * ub[3];
            aR[4] = Kt4c * ub[4];
            float cs = ((aR[0] + aR[1]) + (aR[2] + aR[3])) + (aR[4] + TINY);
            cs = bfly16(cs); cs = bfly32(cs);
            v_ = qop * fast_rcp(cs);
        }
        // G = K~ * û * p*v  — aR already holds K~*û from the last iteration
        // (aR[4] gated => G[4]==0 on q>0, so colG needs no gate).
        float pv = p_ * v_;
        #pragma unroll
        for (int r = 0; r < 5; ++r) G[r] = aR[r] * pv;

        // ---- tens = C1*(G*C2^T), star-decomposed; dots via LDS ----
        #pragma unroll
        for (int r = 0; r < 4; ++r) GL[w][q + 4*r][m] = G[r];   // rows 0..15
        GL[w][j16][m] = G[4];                                    // row 16 (q0)
        // colG[k] = sum_j G[j][k] (row 16 counted once; G[4]==0 on q>0)
        float cg = (G[0] + G[1]) + (G[2] + G[3]) + G[4];
        cg = bfly16(cg); cg = bfly32(cg);
        if (q == 0) GL[w][17][m] = cg;
        // Fm[m] = sum_k colG[k]*C2[mc][k]; H0[m] = sum_k G[0][k]*C2[mc][k]
        float Fm = dot10(&GL[w][17][0], crReg);
        float H0 = dot10(&GL[w][0][0],  crReg);
        // tens[0] = F - H0 (row 0: all bits 1..16 set);
        // tens[s>=1] = H0 + rare extras. Extras popped from the UNION mask:
        // one divergent loop per outer; per bit j one dot10 + 5 gated adds.
        unsigned ex0 = msk[0] & exm; if (q == 0) ex0 = 0u;  // row 0 via Fm
        unsigned ex1 = msk[1] & exm, ex2 = msk[2] & exm;
        unsigned ex3 = msk[3] & exm, ex4 = msk[4] & exm;
        unsigned exu = ((ex0 | ex1) | (ex2 | ex3)) | ex4;
        #pragma unroll
        for (int r = 0; r < 5; ++r) tens[r] = H0;
        while (exu) {
            int j = __builtin_ctz(exu);
            exu &= exu - 1u;
            float dj = dot10(&GL[w][j][0], crReg);
            tens[0] += ((ex0 >> j) & 1u) ? dj : 0.f;
            tens[1] += ((ex1 >> j) & 1u) ? dj : 0.f;
            tens[2] += ((ex2 >> j) & 1u) ? dj : 0.f;
            tens[3] += ((ex3 >> j) & 1u) ? dj : 0.f;
            tens[4] += ((ex4 >> j) & 1u) ? dj : 0.f;
        }
        if (q == 0) tens[0] = Fm - H0;
    }

    // dist = sum G * ((1-a)M + a*constC - 2a*tens); lk2 = lkP2b + rm2 (log2 units)
    float val = 0.f;
    #pragma unroll
    for (int r = 0; r < 5; ++r) {
        float cC = npop[r] * p_ + hC2;
        float lk2r = lkP2b[r] + rm2[r];
        float integ = -(0.1f * LN2) * lk2r - alpha * cC - 2.f * alpha * tens[r];
        bool valid = act && (r < 4 || q == 0);
        val += valid ? G[r] * integ : 0.f;
    }
    val = rowsum16(val);
    val = bfly16(val);
    val = bfly32(val);
    if (lane == 0) out[n * T + t] = val;
}

extern "C" void kernel_launch(void* const* d_in, const int* in_sizes, int n_in,
                              void* d_out, int out_size, void* d_ws, size_t ws_size,
                              hipStream_t stream) {
    const float* x      = (const float*)d_in[0];
    const int*   edge   = (const int*)  d_in[1];
    const float* tmpl   = (const float*)d_in[2];
    const float* F2     = (const float*)d_in[3];
    const float* q0     = (const float*)d_in[4];
    const float* alpha0 = (const float*)d_in[5];
    float*       out    = (float*)d_out;

    // ws layout: Mp [N*100] f32 | masks [N*17] u32 | sqF2 [100] f32  (~2.34 MB)
    float*    wsMp    = (float*)d_ws;
    unsigned* wsMask  = (unsigned*)((char*)d_ws + (size_t)NN * T * MN * 4);
    float*    wsSqF2  = (float*)((char*)d_ws + (size_t)NN * T * MN * 4 + (size_t)NN * S * 4);

    hipLaunchKernelGGL(ltfgw_pre, dim3(NN + 1), dim3(320), 0, stream,
                       x, edge, F2, wsMp, wsMask, wsSqF2);
    hipLaunchKernelGGL(ltfgw_wave, dim3(NN * T / WPB), dim3(BLOCK), 0, stream,
                       edge, tmpl, q0, alpha0, wsMp, wsMask, wsSqF2, out);
}

// Round 7
// 219.314 us; speedup vs baseline: 1.0411x; 1.0411x over previous
//
#include <hip/hip_runtime.h>
#include <math.h>

#define NN   5000
#define DEG  16
#define S    17
#define T    10
#define MN   10
#define D    128
#define NOUT 3
#define NSK  5

#define WPB   8            // waves per block (wave-private work; no barrier)
#define BLOCK (WPB * 64)
#define NEG   -3.0e38f
#define LOG2E 1.44269504088896f
#define LN2   0.69314718055995f
#define TINY  1e-30f       // cs floor: keeps inactive-column v_ finite (0*inf=NaN!)

typedef unsigned uint2v __attribute__((ext_vector_type(2)));

__device__ __forceinline__ float fast_rcp(float x) { return __builtin_amdgcn_rcpf(x); }

#if __has_builtin(__builtin_amdgcn_exp2f)
__device__ __forceinline__ float fast_exp2(float x) { return __builtin_amdgcn_exp2f(x); }
#else
__device__ __forceinline__ float fast_exp2(float x) { return __expf(x * LN2); }
#endif

// DPP row_ror:k — pure-VALU cross-lane within each 16-lane row. The mov+op
// pairs are fused to v_add_f32_dpp/v_max_f32_dpp by GCNDPPCombine
// (bound_ctrl=1), so each stage is one VALU inst.
template <int CTRL>
__device__ __forceinline__ float dpp_movf(float v) {
    return __int_as_float(__builtin_amdgcn_update_dpp(
        0, __float_as_int(v), CTRL, 0xF, 0xF, true));
}
__device__ __forceinline__ float rowsum16(float v) {
    v += dpp_movf<0x121>(v);
    v += dpp_movf<0x122>(v);
    v += dpp_movf<0x124>(v);
    v += dpp_movf<0x128>(v);
    return v;
}
__device__ __forceinline__ float rowmax16(float v) {
    v = fmaxf(v, dpp_movf<0x121>(v));
    v = fmaxf(v, dpp_movf<0x122>(v));
    v = fmaxf(v, dpp_movf<0x124>(v));
    v = fmaxf(v, dpp_movf<0x128>(v));
    return v;
}

// gfx950 permlane-swap butterflies: v + v[lane^16] / v[lane^32] in pure VALU.
__device__ __forceinline__ float bfly16(float v) {
#if __has_builtin(__builtin_amdgcn_permlane16_swap)
    uint2v r = __builtin_amdgcn_permlane16_swap(__float_as_uint(v), __float_as_uint(v),
                                                false, false);
    return __uint_as_float(r[0]) + __uint_as_float(r[1]);
#else
    return v + __int_as_float(__builtin_amdgcn_ds_swizzle(__float_as_int(v), 0x401F));
#endif
}
__device__ __forceinline__ float bfly32(float v) {
#if __has_builtin(__builtin_amdgcn_permlane32_swap)
    uint2v r = __builtin_amdgcn_permlane32_swap(__float_as_uint(v), __float_as_uint(v),
                                                false, false);
    return __uint_as_float(r[0]) + __uint_as_float(r[1]);
#else
    return v + __shfl_xor(v, 32, 64);
#endif
}

// 10-term dot of an LDS row (16B-aligned, 16-float stride) with a register
// array: 3 vector ds_reads (LDS pipe, co-issues with VALU) + 14 VALU, tree
// depth ~3.
__device__ __forceinline__ float dot10(const float* __restrict__ row,
                                       const float* __restrict__ cr) {
    float4 a = *(const float4*)(row);
    float4 b = *(const float4*)(row + 4);
    float2 c = *(const float2*)(row + 8);
    float e0 = fmaf(cr[1], a.y, cr[0] * a.x);
    float e1 = fmaf(cr[3], a.w, cr[2] * a.z);
    float e2 = fmaf(cr[5], b.y, cr[4] * b.x);
    float e3 = fmaf(cr[7], b.w, cr[6] * b.z);
    float e4 = fmaf(cr[9], c.y, cr[8] * c.x);
    return ((e0 + e1) + (e2 + e3)) + e4;
}

// ---------------- Pre-kernel: batch the per-node redundant work ----------------
// (unchanged) Mp[n,c] = xsq[n] - 2*(x[n].F2f[c]); masks[n][s]; sqF2[100].
__global__ __launch_bounds__(320) void ltfgw_pre(
    const float* __restrict__ x,        // [N, D]
    const int*   __restrict__ edge,     // [2, N*DEG]
    const float* __restrict__ F2,       // [T, MN, D] == [100, D] flat
    float*       __restrict__ wsMp,     // [N, 100]  xsq[n] - 2*dot
    unsigned*    __restrict__ wsMask,   // [N, 17]   adjacency bitmasks
    float*       __restrict__ wsSqF2)   // [100]
{
    const int n   = blockIdx.x;
    const int tid = threadIdx.x;
    const int* dst = edge + NN * DEG;

    if (n == NN) {                       // sqF2[c] = ||F2f[c]||^2
        if (tid < T * MN) {
            const float4* fr = (const float4*)(F2 + (size_t)tid * D);
            float acc = 0.f;
            #pragma unroll 8
            for (int i = 0; i < D / 4; ++i) {
                float4 f = fr[i];
                acc += f.x*f.x + f.y*f.y + f.z*f.z + f.w*f.w;
            }
            wsSqF2[tid] = acc;
        }
        return;
    }

    __shared__ int      loc[S];
    __shared__ int      neigh[S][DEG];
    __shared__ unsigned cm[S];
    __shared__ float    xsq_s;

    if (tid < S) { loc[tid] = (tid == 0) ? n : dst[n * DEG + tid - 1]; cm[tid] = 0u; }
    __syncthreads();

    if (tid < S * DEG) neigh[tid >> 4][tid & 15] = dst[loc[tid >> 4] * DEG + (tid & 15)];
    if (tid < 64) {                      // xsq[n] via wave-0 DPP reduce
        float v0 = x[(size_t)n * D + tid];
        float v1 = x[(size_t)n * D + 64 + tid];
        float pp = v0 * v0 + v1 * v1;
        pp = rowsum16(pp);
        pp += __shfl_xor(pp, 16, 64);
        pp += __shfl_xor(pp, 32, 64);
        if (tid == 0) xsq_s = pp;
    }
    __syncthreads();

    if (tid < S * S) {
        int a = tid / S, b = tid % S;
        int la = loc[a], lb = loc[b];
        bool adj = false;
        #pragma unroll
        for (int k = 0; k < DEG; ++k) adj = adj | (neigh[a][k] == lb) | (neigh[b][k] == la);
        if (a != b && adj) atomicOr(&cm[a], 1u << b);
    }
    __syncthreads();

    if (tid < S) wsMask[n * S + tid] = cm[tid];
    if (tid >= 32 && tid < 32 + T * MN) {  // Mp[n,c] = xsq - 2*(x[n].F2f[c])
        int c = tid - 32;
        const float4* fr = (const float4*)(F2 + (size_t)c * D);
        const float4* xr = (const float4*)(x + (size_t)n * D);
        float dotv = 0.f;
        #pragma unroll 8
        for (int d4 = 0; d4 < D / 4; ++d4) {
            float4 f = fr[d4], xv = xr[d4];
            dotv += f.x*xv.x + f.y*xv.y + f.z*xv.z + f.w*xv.w;
        }
        wsMp[n * (T * MN) + c] = xsq_s - 2.f * dotv;
    }
}

// ---------------- Main: one wave = one (node, template) OT problem ----------------
// Round-15: partial revert. R14's 3-item bundle regressed (133.6 -> 140.4 µs,
// VGPR 40->44, achieved occupancy 53->42%): at this inst count the codegen is
// scheduling-lottery-sensitive and the union-extras loop + aR liveness change
// perturbed allocation more than the saved instructions gained. This is the
// exact R13 structure (best verified: 133.6 µs wave / 221.98 µs total) plus
// ONLY the act-mask hoist: lkP2b = NEG on inactive lanes at prologue so the
// per-outer Kt needs no cndmask. exp2(NEG + bounded) == 0.0f exactly (tens is
// provably finite on inactive lanes), so Kt is bit-identical to R13's
// act-gated version. Epilogue's lkP2b+rm2 use is act-gated, unaffected.
// __launch_bounds__: block size ONLY (rounds 2-3: min-waves hint => spills).
__global__ __launch_bounds__(BLOCK) void ltfgw_wave(
    const int*      __restrict__ edge,     // [2, N*DEG]
    const float*    __restrict__ tmpl,     // [T, MN, MN]
    const float*    __restrict__ q0,       // [T, MN]
    const float*    __restrict__ alpha0,   // [1]
    const float*    __restrict__ wsMp,     // [N, 100]
    const unsigned* __restrict__ wsMask,   // [N, 17]
    const float*    __restrict__ wsSqF2,   // [100]
    float*          __restrict__ out)      // [N, T]
{
    const int tid  = threadIdx.x;
    const int w    = tid >> 6;
    const int gid  = blockIdx.x * WPB + w;   // flat (node, template) id
    const int n    = gid / T;
    const int t    = gid - n * T;
    const int lane = tid & 63;
    const int q    = lane >> 4;
    const int m    = lane & 15;
    const bool act = (m < MN);
    const int mc   = act ? m : (MN - 1);

    __shared__ __align__(16) float C2l[WPB][MN][17]; // wave-private; stride 17
    __shared__ __align__(16) float GL[WPB][19][16];  // rows 0-16: G; 17: colG; 18: dump
    __shared__ __align__(16) float QL[WPB][16];      // q-weights (tail zeroed)

    const int* dst = edge + NN * DEG;

    // q = softmax(q0[t]) via DPP row reduction (all lanes)
    float vq = q0[t * MN + mc];
    float zq = act ? vq : NEG;
    float mq = rowmax16(zq);
    float sq = rowsum16(__expf(zq - mq));     // inactive: exp(NEG-mq)=0
    const float qm = __expf(vq - (mq + __logf(sq)));   // valid on act lanes
    if (q == 0) QL[w][m] = act ? qm : 0.f;    // q vector to LDS (tail = 0)
    // C2 = softmax(tmpl, axis=1): active lane m of quad 0 does column m
    if (act && q == 0) {
        float v[MN]; float cmx = NEG;
        #pragma unroll
        for (int i = 0; i < MN; ++i) { v[i] = tmpl[t * MN * MN + i * MN + m]; cmx = fmaxf(cmx, v[i]); }
        float ssum = 0.f;
        #pragma unroll
        for (int i = 0; i < MN; ++i) { v[i] = __expf(v[i] - cmx); ssum += v[i]; }
        float inv = fast_rcp(ssum);
        #pragma unroll
        for (int i = 0; i < MN; ++i) C2l[w][i][m] = v[i] * inv;
    }

    // per-row gathers (L1/L2-resident ws): rows sr[r] = q+4r, clamp 16
    int sr[5];
    #pragma unroll
    for (int r = 0; r < 5; ++r) { int s0 = q + 4 * r; sr[r] = (s0 > 16) ? 16 : s0; }
    unsigned msk[5]; float npop[5]; float Mp[5];
    const int cidx = t * MN + mc;
    #pragma unroll
    for (int r = 0; r < 5; ++r) {
        int lr  = (sr[r] == 0) ? n : dst[n * DEG + sr[r] - 1];
        msk[r]  = wsMask[n * S + sr[r]];
        npop[r] = (float)__popc(msk[r]);
        Mp[r]   = wsMp[lr * (T * MN) + cidx];
    }
    const float sqf2c = wsSqF2[cidx];

    // C2 row mc in registers (stride-17 b32 reads: 10 distinct banks, no
    // conflict; same-wave LDS RAW ordered by compiler lgkmcnt)
    float crReg[MN];
    #pragma unroll
    for (int k = 0; k < MN; ++k) crReg[k] = C2l[w][mc][k];

    // hC2 = sum_k C2[mc][k]^2 q[k]; qC2m = sum_k C2[mc][k] q[k]
    // (q[k] broadcast from LDS; replaces the 16-step rotation pair)
    float hC2 = 0.f, qC2m = 0.f;
    {
        float ql[MN];
        #pragma unroll
        for (int k = 0; k < MN; ++k) ql[k] = QL[w][k];
        #pragma unroll
        for (int k = 0; k < MN; ++k) {
            float cq = crReg[k] * ql[k];
            qC2m += cq;
            hC2  = fmaf(crReg[k], cq, hC2);
        }
    }

    const float alpha = fast_rcp(1.f + __expf(-alpha0[0]));
    const float oma   = 1.f - alpha;
    const float p_    = 1.f / (float)S;
    const float fa42  = 40.f * alpha * LOG2E; // log2K = lkP2 + fa42*tens
    const float qop   = qm * (float)S;        // q/p for folded v-update
    const unsigned exm = act ? 0x1FFFEu : 0u; // extras mask (skip bit 0; gate act)
    const int j16  = (q == 0) ? 16 : 18;      // row-16 G write: q>0 -> dump row

    // lkP2b = log2-domain linear part, pre-shifted by hoisted row stabilizer.
    // Inactive lanes get NEG => Kt = exp2(NEG + bounded) = 0 exactly, with no
    // per-outer cndmask (act-mask hoist; only R14 item retained).
    float lkP2b[5], rm2[5];
    {
        const float nl2e10 = -10.f * LOG2E;
        #pragma unroll
        for (int r = 0; r < 5; ++r) {
            float M_ = Mp[r] + sqf2c;             // xsq + sqf2 - 2*dot
            float cC = npop[r] * p_ + hC2;        // hC1 = popc/S
            float lk2 = nl2e10 * (oma * M_ + 2.f * alpha * cC);
            rm2[r]   = rowmax16(act ? lk2 : NEG) + 14.4f;  // overflow headroom
            lkP2b[r] = act ? (lk2 - rm2[r]) : NEG;
        }
    }

    // outer 0 analytic: G0 = p q^T => tens0[r] = p * qC2m * popc(msk[r])
    float tens[5], Kt[5], ub[5], v_, G[5];
    {
        float pq = p_ * qC2m;
        #pragma unroll
        for (int r = 0; r < 5; ++r) tens[r] = pq * npop[r];
    }

    for (int o = 1; o <= NOUT; ++o) {
        // K~ = exp2(lkP2b + fa42*tens)  (rowmax hoisted; Sinkhorn scale-invariant;
        // inactive lanes: exp2(NEG+bounded)=0, no cndmask)
        #pragma unroll
        for (int r = 0; r < 5; ++r)
            Kt[r] = fast_exp2(fmaf(fa42, tens[r], lkP2b[r]));
        float Kt4c = (q == 0) ? Kt[4] : 0.f;   // row 16 counted once in cs

        // folded exp-domain Sinkhorn: û = rcp(K~ v); v = (Sq)*rcp(K~^T û)
        // iter 0 peeled (v == 1). cs floored by TINY so inactive columns
        // (all-Kt==0) give finite v_; Kt*v_ stays exactly 0 there.
        #pragma unroll
        for (int r = 0; r < 5; ++r) ub[r] = fast_rcp(rowsum16(Kt[r]));
        {
            float a0 = Kt[0] * ub[0], a1 = Kt[1] * ub[1];
            float a2 = Kt[2] * ub[2], a3 = Kt[3] * ub[3];
            float a4 = fmaf(Kt4c, ub[4], TINY);
            float cs = ((a0 + a1) + (a2 + a3)) + a4;
            cs = bfly16(cs); cs = bfly32(cs);
            v_ = qop * fast_rcp(cs);
        }
        #pragma unroll
        for (int it = 1; it < NSK; ++it) {
            #pragma unroll
            for (int r = 0; r < 5; ++r)
                ub[r] = fast_rcp(rowsum16(Kt[r] * v_));
            float a0 = Kt[0] * ub[0], a1 = Kt[1] * ub[1];
            float a2 = Kt[2] * ub[2], a3 = Kt[3] * ub[3];
            float a4 = fmaf(Kt4c, ub[4], TINY);
            float cs = ((a0 + a1) + (a2 + a3)) + a4;
            cs = bfly16(cs); cs = bfly32(cs);
            v_ = qop * fast_rcp(cs);
        }
        float pv = p_ * v_;
        #pragma unroll
        for (int r = 0; r < 5; ++r) G[r] = Kt[r] * ub[r] * pv;

        // ---- tens = C1*(G*C2^T), star-decomposed; dots via LDS ----
        #pragma unroll
        for (int r = 0; r < 4; ++r) GL[w][q + 4*r][m] = G[r];   // rows 0..15
        GL[w][j16][m] = G[4];                                    // row 16 (q0)
        // colG[k] = sum_j G[j][k] (row 16 counted once); stash in GL row 17
        float cg = (G[0] + G[1]) + (G[2] + G[3]) + ((q == 0) ? G[4] : 0.f);
        cg = bfly16(cg); cg = bfly32(cg);
        if (q == 0) GL[w][17][m] = cg;
        // Fm[m] = sum_k colG[k]*C2[mc][k]; H0[m] = sum_k G[0][k]*C2[mc][k]
        float Fm = dot10(&GL[w][17][0], crReg);
        float H0 = dot10(&GL[w][0][0],  crReg);
        // tens[0] = F - H0 (row 0: all bits 1..16 set);
        // tens[s>=1] = H0 + rare extras (10-term LDS dots, ~0.1 bits/row).
        #pragma unroll
        for (int r = 0; r < 5; ++r) {
            unsigned ex = msk[r] & exm;    // extras: bits 1..16
            if (r == 0) ex = (q == 0) ? 0u : ex;   // row 0 handled via Fm
            float tn = H0;                 // bit 0 always set for s>=1
            while (ex) {
                int j = __builtin_ctz(ex);
                ex &= ex - 1u;
                tn += dot10(&GL[w][j][0], crReg);
            }
            tens[r] = tn;
        }
        if (q == 0) tens[0] = Fm - H0;
    }

    // dist = sum G * ((1-a)M + a*constC - 2a*tens); lk2 = lkP2b + rm2 (log2 units)
    float val = 0.f;
    #pragma unroll
    for (int r = 0; r < 5; ++r) {
        float cC = npop[r] * p_ + hC2;
        float lk2r = lkP2b[r] + rm2[r];
        float integ = -(0.1f * LN2) * lk2r - alpha * cC - 2.f * alpha * tens[r];
        bool valid = act && (r < 4 || q == 0);
        val += valid ? G[r] * integ : 0.f;
    }
    val = rowsum16(val);
    val = bfly16(val);
    val = bfly32(val);
    if (lane == 0) out[n * T + t] = val;
}

extern "C" void kernel_launch(void* const* d_in, const int* in_sizes, int n_in,
                              void* d_out, int out_size, void* d_ws, size_t ws_size,
                              hipStream_t stream) {
    const float* x      = (const float*)d_in[0];
    const int*   edge   = (const int*)  d_in[1];
    const float* tmpl   = (const float*)d_in[2];
    const float* F2     = (const float*)d_in[3];
    const float* q0     = (const float*)d_in[4];
    const float* alpha0 = (const float*)d_in[5];
    float*       out    = (float*)d_out;

    // ws layout: Mp [N*100] f32 | masks [N*17] u32 | sqF2 [100] f32  (~2.34 MB)
    float*    wsMp    = (float*)d_ws;
    unsigned* wsMask  = (unsigned*)((char*)d_ws + (size_t)NN * T * MN * 4);
    float*    wsSqF2  = (float*)((char*)d_ws + (size_t)NN * T * MN * 4 + (size_t)NN * S * 4);

    hipLaunchKernelGGL(ltfgw_pre, dim3(NN + 1), dim3(320), 0, stream,
                       x, edge, F2, wsMp, wsMask, wsSqF2);
    hipLaunchKernelGGL(ltfgw_wave, dim3(NN * T / WPB), dim3(BLOCK), 0, stream,
                       edge, tmpl, q0, alpha0, wsMp, wsMask, wsSqF2, out);
}

// Round 8
// 200.779 us; speedup vs baseline: 1.1372x; 1.0923x over previous
//
#include <hip/hip_runtime.h>
#include <math.h>

#define NN   5000
#define DEG  16
#define S    17
#define T    10
#define MN   10
#define D    128
#define NOUT 3
#define NSK  5

#define WPB   8            // waves per block (wave-private work; no barrier)
#define PPW   2            // problems per wave (lanes 0-31 / 32-63)
#define BLOCK (WPB * 64)
#define RS    9            // row slots per lane: ceil(17 rows / 2 quads)
#define NEG   -3.0e38f
#define LOG2E 1.44269504088896f
#define LN2   0.69314718055995f
#define TINY  1e-30f       // cs floor: keeps inactive-column v_ finite (0*inf=NaN!)

typedef unsigned uint2v __attribute__((ext_vector_type(2)));

__device__ __forceinline__ float fast_rcp(float x) { return __builtin_amdgcn_rcpf(x); }

#if __has_builtin(__builtin_amdgcn_exp2f)
__device__ __forceinline__ float fast_exp2(float x) { return __builtin_amdgcn_exp2f(x); }
#else
__device__ __forceinline__ float fast_exp2(float x) { return __expf(x * LN2); }
#endif

// DPP row_ror:k — pure-VALU cross-lane within each 16-lane row (fused to
// v_add/max_f32_dpp by GCNDPPCombine).
template <int CTRL>
__device__ __forceinline__ float dpp_movf(float v) {
    return __int_as_float(__builtin_amdgcn_update_dpp(
        0, __float_as_int(v), CTRL, 0xF, 0xF, true));
}
__device__ __forceinline__ float rowsum16(float v) {
    v += dpp_movf<0x121>(v);
    v += dpp_movf<0x122>(v);
    v += dpp_movf<0x124>(v);
    v += dpp_movf<0x128>(v);
    return v;
}
__device__ __forceinline__ float rowmax16(float v) {
    v = fmaxf(v, dpp_movf<0x121>(v));
    v = fmaxf(v, dpp_movf<0x122>(v));
    v = fmaxf(v, dpp_movf<0x124>(v));
    v = fmaxf(v, dpp_movf<0x128>(v));
    return v;
}

// gfx950 permlane16-swap butterfly: v + v[lane^16] in pure VALU.
__device__ __forceinline__ float bfly16(float v) {
#if __has_builtin(__builtin_amdgcn_permlane16_swap)
    uint2v r = __builtin_amdgcn_permlane16_swap(__float_as_uint(v), __float_as_uint(v),
                                                false, false);
    return __uint_as_float(r[0]) + __uint_as_float(r[1]);
#else
    return v + __int_as_float(__builtin_amdgcn_ds_swizzle(__float_as_int(v), 0x401F));
#endif
}

// 10-term dot of an LDS row (16B-aligned, 16-float stride) with a register
// array: 3 vector ds_reads (LDS pipe, co-issues with VALU) + 14 VALU, depth ~3.
__device__ __forceinline__ float dot10(const float* __restrict__ row,
                                       const float* __restrict__ cr) {
    float4 a = *(const float4*)(row);
    float4 b = *(const float4*)(row + 4);
    float2 c = *(const float2*)(row + 8);
    float e0 = fmaf(cr[1], a.y, cr[0] * a.x);
    float e1 = fmaf(cr[3], a.w, cr[2] * a.z);
    float e2 = fmaf(cr[5], b.y, cr[4] * b.x);
    float e3 = fmaf(cr[7], b.w, cr[6] * b.z);
    float e4 = fmaf(cr[9], c.y, cr[8] * c.x);
    return ((e0 + e1) + (e2 + e3)) + e4;
}

// ---------------- Pre-kernel: batch the per-node redundant work ----------------
// (unchanged) Mp[n,c] = xsq[n] - 2*(x[n].F2f[c]); masks[n][s]; sqF2[100].
__global__ __launch_bounds__(320) void ltfgw_pre(
    const float* __restrict__ x,        // [N, D]
    const int*   __restrict__ edge,     // [2, N*DEG]
    const float* __restrict__ F2,       // [T, MN, D] == [100, D] flat
    float*       __restrict__ wsMp,     // [N, 100]  xsq[n] - 2*dot
    unsigned*    __restrict__ wsMask,   // [N, 17]   adjacency bitmasks
    float*       __restrict__ wsSqF2)   // [100]
{
    const int n   = blockIdx.x;
    const int tid = threadIdx.x;
    const int* dst = edge + NN * DEG;

    if (n == NN) {                       // sqF2[c] = ||F2f[c]||^2
        if (tid < T * MN) {
            const float4* fr = (const float4*)(F2 + (size_t)tid * D);
            float acc = 0.f;
            #pragma unroll 8
            for (int i = 0; i < D / 4; ++i) {
                float4 f = fr[i];
                acc += f.x*f.x + f.y*f.y + f.z*f.z + f.w*f.w;
            }
            wsSqF2[tid] = acc;
        }
        return;
    }

    __shared__ int      loc[S];
    __shared__ int      neigh[S][DEG];
    __shared__ unsigned cm[S];
    __shared__ float    xsq_s;

    if (tid < S) { loc[tid] = (tid == 0) ? n : dst[n * DEG + tid - 1]; cm[tid] = 0u; }
    __syncthreads();

    if (tid < S * DEG) neigh[tid >> 4][tid & 15] = dst[loc[tid >> 4] * DEG + (tid & 15)];
    if (tid < 64) {                      // xsq[n] via wave-0 DPP reduce
        float v0 = x[(size_t)n * D + tid];
        float v1 = x[(size_t)n * D + 64 + tid];
        float pp = v0 * v0 + v1 * v1;
        pp = rowsum16(pp);
        pp += __shfl_xor(pp, 16, 64);
        pp += __shfl_xor(pp, 32, 64);
        if (tid == 0) xsq_s = pp;
    }
    __syncthreads();

    if (tid < S * S) {
        int a = tid / S, b = tid % S;
        int la = loc[a], lb = loc[b];
        bool adj = false;
        #pragma unroll
        for (int k = 0; k < DEG; ++k) adj = adj | (neigh[a][k] == lb) | (neigh[b][k] == la);
        if (a != b && adj) atomicOr(&cm[a], 1u << b);
    }
    __syncthreads();

    if (tid < S) wsMask[n * S + tid] = cm[tid];
    if (tid >= 32 && tid < 32 + T * MN) {  // Mp[n,c] = xsq - 2*(x[n].F2f[c])
        int c = tid - 32;
        const float4* fr = (const float4*)(F2 + (size_t)c * D);
        const float4* xr = (const float4*)(x + (size_t)n * D);
        float dotv = 0.f;
        #pragma unroll 8
        for (int d4 = 0; d4 < D / 4; ++d4) {
            float4 f = fr[d4], xv = xr[d4];
            dotv += f.x*xv.x + f.y*xv.y + f.z*xv.z + f.w*xv.w;
        }
        wsMp[n * (T * MN) + c] = xsq_s - 2.f * dotv;
    }
}

// ---------------- Main: one wave = TWO (node, template) OT problems ----------------
// Round-16 restructure. Lanes 0-31 = problem A, 32-63 = problem B. Within a
// problem: 2 quads, lane (ql,m); lane owns rows s = 2r+ql, r=0..8 (pad at
// ql=1,r=8). vs R15: waves halve (25k), per-wave r-work 5->9 (net ~0.9x issue),
// per-iter independent chains 5->9 (ILP for the latency-bound scheduler), and
// the column reduce is bfly16 ONLY (bfly32 leaves the 15x sink chain; rowsum16
// DPP ops serve both problems for free). Row 16 exists exactly once (ql=0,r=8)
// — the pad gate replaces the old Kt4c replication. NaN discipline (R12): pad
// ub = rcp(0) = inf, so gates apply AFTER the Kt*ub product; cs keeps TINY.
// VGPR relief: npop recomputed via popc; rm2 parked in LDS (epilogue-only).
// __launch_bounds__: block size ONLY (rounds 2-3: min-waves hint => spills).
__global__ __launch_bounds__(BLOCK) void ltfgw_wave(
    const int*      __restrict__ edge,     // [2, N*DEG]
    const float*    __restrict__ tmpl,     // [T, MN, MN]
    const float*    __restrict__ q0,       // [T, MN]
    const float*    __restrict__ alpha0,   // [1]
    const float*    __restrict__ wsMp,     // [N, 100]
    const unsigned* __restrict__ wsMask,   // [N, 17]
    const float*    __restrict__ wsSqF2,   // [100]
    float*          __restrict__ out)      // [N, T]
{
    const int tid  = threadIdx.x;
    const int w    = tid >> 6;
    const int lane = tid & 63;
    const int half = lane >> 5;              // which problem in the wave
    const int q    = lane >> 4;              // global quad 0..3
    const int ql   = q & 1;                  // quad within problem
    const int m    = lane & 15;
    const bool act = (m < MN);
    const int mc   = act ? m : (MN - 1);
    const bool pad8 = (ql == 1);             // slot r=8 is a pad on ql==1
    const int gid  = (blockIdx.x * WPB + w) * PPW + half;
    const int n    = gid / T;
    const int t    = gid - n * T;

    __shared__ __align__(16) float C2l[WPB][PPW][MN][17]; // per-problem C2
    __shared__ __align__(16) float GL [WPB][PPW][19][16]; // 0-16 G rows;17 colG;18 dump
    __shared__ __align__(16) float QL [WPB][PPW][16];     // q-weights (tail 0)
    __shared__               float RM [WPB][PPW][20];     // rm2 per row (epilogue)

    const int* dst = edge + NN * DEG;

    // q = softmax(q0[t]) via DPP row reduction (quads of a problem share t)
    float vq = q0[t * MN + mc];
    float zq = act ? vq : NEG;
    float mq = rowmax16(zq);
    float sq = rowsum16(__expf(zq - mq));     // inactive: exp(NEG-mq)=0
    const float qm = __expf(vq - (mq + __logf(sq)));   // valid on act lanes
    if (ql == 0) QL[w][half][m] = act ? qm : 0.f;      // per-problem q vector
    // C2 = softmax(tmpl, axis=1): active lane m of quad ql==0 does column m
    if (act && ql == 0) {
        float v[MN]; float cmx = NEG;
        #pragma unroll
        for (int i = 0; i < MN; ++i) { v[i] = tmpl[t * MN * MN + i * MN + m]; cmx = fmaxf(cmx, v[i]); }
        float ssum = 0.f;
        #pragma unroll
        for (int i = 0; i < MN; ++i) { v[i] = __expf(v[i] - cmx); ssum += v[i]; }
        float inv = fast_rcp(ssum);
        #pragma unroll
        for (int i = 0; i < MN; ++i) C2l[w][half][i][m] = v[i] * inv;
    }

    // per-row gathers (L1/L2-resident ws): rows s = 2r+ql, clamp 16 (pad)
    unsigned msk[RS]; float Mp[RS];
    const int cidx = t * MN + mc;
    #pragma unroll
    for (int r = 0; r < RS; ++r) {
        int s   = 2 * r + ql; s = (s > 16) ? 16 : s;
        int lr  = (s == 0) ? n : dst[n * DEG + s - 1];
        msk[r]  = wsMask[n * S + s];
        Mp[r]   = wsMp[lr * (T * MN) + cidx];
    }
    if (pad8) msk[8] = 0u;                    // pad slot contributes nothing
    const float sqf2c = wsSqF2[cidx];

    // C2 row mc in registers (same-wave LDS RAW ordered by compiler lgkmcnt)
    float crReg[MN];
    #pragma unroll
    for (int k = 0; k < MN; ++k) crReg[k] = C2l[w][half][mc][k];

    // hC2 = sum_k C2[mc][k]^2 q[k]; qC2m = sum_k C2[mc][k] q[k]
    float hC2 = 0.f, qC2m = 0.f;
    {
        float ql_[MN];
        #pragma unroll
        for (int k = 0; k < MN; ++k) ql_[k] = QL[w][half][k];
        #pragma unroll
        for (int k = 0; k < MN; ++k) {
            float cq = crReg[k] * ql_[k];
            qC2m += cq;
            hC2  = fmaf(crReg[k], cq, hC2);
        }
    }

    const float alpha = fast_rcp(1.f + __expf(-alpha0[0]));
    const float oma   = 1.f - alpha;
    const float p_    = 1.f / (float)S;
    const float fa42  = 40.f * alpha * LOG2E; // log2K = lkP2 + fa42*tens
    const float qop   = qm * (float)S;        // q/p for folded v-update
    const unsigned exm = act ? 0x1FFFEu : 0u; // extras mask (skip bit 0; gate act)

    // lkP2b = log2-domain linear part, pre-shifted by hoisted row stabilizer.
    // NEG on inactive lanes AND the pad slot => Kt = 0 with no per-outer mask.
    // rm2 parked in LDS (read only in the epilogue; quad-uniform broadcast).
    float lkP2b[RS];
    {
        const float nl2e10 = -10.f * LOG2E;
        #pragma unroll
        for (int r = 0; r < RS; ++r) {
            int s = 2 * r + ql; s = (s > 16) ? 16 : s;
            float M_  = Mp[r] + sqf2c;             // xsq + sqf2 - 2*dot
            float cC  = (float)__popc(msk[r]) * p_ + hC2;
            float lk2 = nl2e10 * (oma * M_ + 2.f * alpha * cC);
            float rm2 = rowmax16(act ? lk2 : NEG) + 14.4f;  // overflow headroom
            bool vld  = !(pad8 && r == 8);
            lkP2b[r]  = (act && vld) ? (lk2 - rm2) : NEG;
            if (m == 0 && vld) RM[w][half][s] = rm2;
        }
    }

    // outer 0 analytic: G0 = p q^T => tens0[r] = p * qC2m * popc(msk[r])
    float tens[RS], Kt[RS], ub[RS], v_, G[RS];
    {
        float pq = p_ * qC2m;
        #pragma unroll
        for (int r = 0; r < RS; ++r) tens[r] = pq * (float)__popc(msk[r]);
    }

    for (int o = 1; o <= NOUT; ++o) {
        // K~ = exp2(lkP2b + fa42*tens): 0 on inactive lanes and pad slot
        #pragma unroll
        for (int r = 0; r < RS; ++r)
            Kt[r] = fast_exp2(fmaf(fa42, tens[r], lkP2b[r]));

        // folded exp-domain Sinkhorn: û = rcp(K~ v); v = (Sq)*rcp(K~^T û)
        // iter 0 peeled (v == 1). Column reduce = bfly16 only (2 quads).
        // Pad slot: ub[8]=inf, a8=0*inf=NaN — gated AFTER the product (R12!).
        #pragma unroll
        for (int r = 0; r < RS; ++r) ub[r] = fast_rcp(rowsum16(Kt[r]));
        {
            float a8  = Kt[8] * ub[8];
            float a8g = pad8 ? 0.f : a8;
            float cs  = (((Kt[0]*ub[0] + Kt[1]*ub[1]) + (Kt[2]*ub[2] + Kt[3]*ub[3]))
                       + ((Kt[4]*ub[4] + Kt[5]*ub[5]) + (Kt[6]*ub[6] + Kt[7]*ub[7])))
                       + (a8g + TINY);
            cs = bfly16(cs);
            v_ = qop * fast_rcp(cs);
        }
        #pragma unroll
        for (int it = 1; it < NSK; ++it) {
            #pragma unroll
            for (int r = 0; r < RS; ++r)
                ub[r] = fast_rcp(rowsum16(Kt[r] * v_));
            float a8  = Kt[8] * ub[8];
            float a8g = pad8 ? 0.f : a8;
            float cs  = (((Kt[0]*ub[0] + Kt[1]*ub[1]) + (Kt[2]*ub[2] + Kt[3]*ub[3]))
                       + ((Kt[4]*ub[4] + Kt[5]*ub[5]) + (Kt[6]*ub[6] + Kt[7]*ub[7])))
                       + (a8g + TINY);
            cs = bfly16(cs);
            v_ = qop * fast_rcp(cs);
        }
        float pv = p_ * v_;
        #pragma unroll
        for (int r = 0; r < RS; ++r) G[r] = Kt[r] * ub[r] * pv;  // G[8]=NaN on pad

        // ---- tens = C1*(G*C2^T), star-decomposed; dots via LDS ----
        #pragma unroll
        for (int r = 0; r < 8; ++r) GL[w][half][2*r + ql][m] = G[r];  // rows 0..15
        GL[w][half][pad8 ? 18 : 16][m] = G[8];                        // row 16 / dump
        // colG[k] = sum over the problem's 17 rows (pad gated; NaN discarded)
        float cg = (((G[0]+G[1]) + (G[2]+G[3])) + ((G[4]+G[5]) + (G[6]+G[7])))
                 + (pad8 ? 0.f : G[8]);
        cg = bfly16(cg);
        if (ql == 0) GL[w][half][17][m] = cg;
        // Fm[m] = sum_k colG[k]*C2[mc][k]; H0[m] = sum_k G[0][k]*C2[mc][k]
        float Fm = dot10(&GL[w][half][17][0], crReg);
        float H0 = dot10(&GL[w][half][0][0],  crReg);
        // tens: row 0 (ql=0,r=0) = Fm - H0 (all bits 1..16 set);
        // rows s>=1 = H0 + rare extras (10-term LDS dots, ~0.1 bits/row).
        #pragma unroll
        for (int r = 0; r < RS; ++r) {
            unsigned ex = msk[r] & exm;              // extras: bits 1..16
            if (r == 0) ex = (ql == 0) ? 0u : ex;    // row 0 handled via Fm
            float tn = H0;                           // bit 0 always set for s>=1
            while (ex) {
                int j = __builtin_ctz(ex);
                ex &= ex - 1u;
                tn += dot10(&GL[w][half][j][0], crReg);
            }
            tens[r] = tn;
        }
        if (ql == 0) tens[0] = Fm - H0;
    }

    // dist = sum G * ((1-a)M + a*constC - 2a*tens); lk2 = lkP2b + rm2 (log2)
    float val = 0.f;
    #pragma unroll
    for (int r = 0; r < RS; ++r) {
        int s = 2 * r + ql; s = (s > 16) ? 16 : s;
        float cC   = (float)__popc(msk[r]) * p_ + hC2;
        float lk2r = lkP2b[r] + RM[w][half][s];
        float integ = -(0.1f * LN2) * lk2r - alpha * cC - 2.f * alpha * tens[r];
        bool valid = act && !(pad8 && r == 8);
        val += valid ? G[r] * integ : 0.f;
    }
    val = rowsum16(val);
    val = bfly16(val);
    if ((lane & 31) == 0) out[gid] = val;
}

extern "C" void kernel_launch(void* const* d_in, const int* in_sizes, int n_in,
                              void* d_out, int out_size, void* d_ws, size_t ws_size,
                              hipStream_t stream) {
    const float* x      = (const float*)d_in[0];
    const int*   edge   = (const int*)  d_in[1];
    const float* tmpl   = (const float*)d_in[2];
    const float* F2     = (const float*)d_in[3];
    const float* q0     = (const float*)d_in[4];
    const float* alpha0 = (const float*)d_in[5];
    float*       out    = (float*)d_out;

    // ws layout: Mp [N*100] f32 | masks [N*17] u32 | sqF2 [100] f32  (~2.34 MB)
    float*    wsMp    = (float*)d_ws;
    unsigned* wsMask  = (unsigned*)((char*)d_ws + (size_t)NN * T * MN * 4);
    float*    wsSqF2  = (float*)((char*)d_ws + (size_t)NN * T * MN * 4 + (size_t)NN * S * 4);

    hipLaunchKernelGGL(ltfgw_pre, dim3(NN + 1), dim3(320), 0, stream,
                       x, edge, F2, wsMp, wsMask, wsSqF2);
    hipLaunchKernelGGL(ltfgw_wave, dim3(NN * T / (WPB * PPW)), dim3(BLOCK), 0, stream,
                       edge, tmpl, q0, alpha0, wsMp, wsMask, wsSqF2, out);
}

// Round 9
// 195.541 us; speedup vs baseline: 1.1676x; 1.0268x over previous
//
#include <hip/hip_runtime.h>
#include <math.h>

#define NN   5000
#define DEG  16
#define S    17
#define T    10
#define MN   10
#define D    128
#define NOUT 3
#define NSK  5

#define WPB   4            // waves per block. R17: 8->4 — one wave per SIMD per
                           // block, so co-resident waves on a SIMD come from
                           // different blocks (different start times) and their
                           // chain stalls desynchronize; finer ramp/tail fill.
#define PPW   2            // problems per wave (lanes 0-31 / 32-63)
#define BLOCK (WPB * 64)
#define RS    9            // row slots per lane: ceil(17 rows / 2 quads)
#define NEG   -3.0e38f
#define LOG2E 1.44269504088896f
#define LN2   0.69314718055995f
#define TINY  1e-30f       // cs floor: keeps inactive-column v_ finite (0*inf=NaN!)

typedef unsigned uint2v __attribute__((ext_vector_type(2)));

__device__ __forceinline__ float fast_rcp(float x) { return __builtin_amdgcn_rcpf(x); }

#if __has_builtin(__builtin_amdgcn_exp2f)
__device__ __forceinline__ float fast_exp2(float x) { return __builtin_amdgcn_exp2f(x); }
#else
__device__ __forceinline__ float fast_exp2(float x) { return __expf(x * LN2); }
#endif

// DPP row_ror:k — pure-VALU cross-lane within each 16-lane row (fused to
// v_add/max_f32_dpp by GCNDPPCombine).
template <int CTRL>
__device__ __forceinline__ float dpp_movf(float v) {
    return __int_as_float(__builtin_amdgcn_update_dpp(
        0, __float_as_int(v), CTRL, 0xF, 0xF, true));
}
__device__ __forceinline__ float rowsum16(float v) {
    v += dpp_movf<0x121>(v);
    v += dpp_movf<0x122>(v);
    v += dpp_movf<0x124>(v);
    v += dpp_movf<0x128>(v);
    return v;
}
__device__ __forceinline__ float rowmax16(float v) {
    v = fmaxf(v, dpp_movf<0x121>(v));
    v = fmaxf(v, dpp_movf<0x122>(v));
    v = fmaxf(v, dpp_movf<0x124>(v));
    v = fmaxf(v, dpp_movf<0x128>(v));
    return v;
}

// gfx950 permlane16-swap butterfly: v + v[lane^16] in pure VALU.
__device__ __forceinline__ float bfly16(float v) {
#if __has_builtin(__builtin_amdgcn_permlane16_swap)
    uint2v r = __builtin_amdgcn_permlane16_swap(__float_as_uint(v), __float_as_uint(v),
                                                false, false);
    return __uint_as_float(r[0]) + __uint_as_float(r[1]);
#else
    return v + __int_as_float(__builtin_amdgcn_ds_swizzle(__float_as_int(v), 0x401F));
#endif
}

// 10-term dot of an LDS row (16B-aligned, 16-float stride) with a register
// array: 3 vector ds_reads (LDS pipe, co-issues with VALU) + 14 VALU, depth ~3.
__device__ __forceinline__ float dot10(const float* __restrict__ row,
                                       const float* __restrict__ cr) {
    float4 a = *(const float4*)(row);
    float4 b = *(const float4*)(row + 4);
    float2 c = *(const float2*)(row + 8);
    float e0 = fmaf(cr[1], a.y, cr[0] * a.x);
    float e1 = fmaf(cr[3], a.w, cr[2] * a.z);
    float e2 = fmaf(cr[5], b.y, cr[4] * b.x);
    float e3 = fmaf(cr[7], b.w, cr[6] * b.z);
    float e4 = fmaf(cr[9], c.y, cr[8] * c.x);
    return ((e0 + e1) + (e2 + e3)) + e4;
}

// ---------------- Pre-kernel: batch the per-node redundant work ----------------
// (unchanged) Mp[n,c] = xsq[n] - 2*(x[n].F2f[c]); masks[n][s]; sqF2[100].
__global__ __launch_bounds__(320) void ltfgw_pre(
    const float* __restrict__ x,        // [N, D]
    const int*   __restrict__ edge,     // [2, N*DEG]
    const float* __restrict__ F2,       // [T, MN, D] == [100, D] flat
    float*       __restrict__ wsMp,     // [N, 100]  xsq[n] - 2*dot
    unsigned*    __restrict__ wsMask,   // [N, 17]   adjacency bitmasks
    float*       __restrict__ wsSqF2)   // [100]
{
    const int n   = blockIdx.x;
    const int tid = threadIdx.x;
    const int* dst = edge + NN * DEG;

    if (n == NN) {                       // sqF2[c] = ||F2f[c]||^2
        if (tid < T * MN) {
            const float4* fr = (const float4*)(F2 + (size_t)tid * D);
            float acc = 0.f;
            #pragma unroll 8
            for (int i = 0; i < D / 4; ++i) {
                float4 f = fr[i];
                acc += f.x*f.x + f.y*f.y + f.z*f.z + f.w*f.w;
            }
            wsSqF2[tid] = acc;
        }
        return;
    }

    __shared__ int      loc[S];
    __shared__ int      neigh[S][DEG];
    __shared__ unsigned cm[S];
    __shared__ float    xsq_s;

    if (tid < S) { loc[tid] = (tid == 0) ? n : dst[n * DEG + tid - 1]; cm[tid] = 0u; }
    __syncthreads();

    if (tid < S * DEG) neigh[tid >> 4][tid & 15] = dst[loc[tid >> 4] * DEG + (tid & 15)];
    if (tid < 64) {                      // xsq[n] via wave-0 DPP reduce
        float v0 = x[(size_t)n * D + tid];
        float v1 = x[(size_t)n * D + 64 + tid];
        float pp = v0 * v0 + v1 * v1;
        pp = rowsum16(pp);
        pp += __shfl_xor(pp, 16, 64);
        pp += __shfl_xor(pp, 32, 64);
        if (tid == 0) xsq_s = pp;
    }
    __syncthreads();

    if (tid < S * S) {
        int a = tid / S, b = tid % S;
        int la = loc[a], lb = loc[b];
        bool adj = false;
        #pragma unroll
        for (int k = 0; k < DEG; ++k) adj = adj | (neigh[a][k] == lb) | (neigh[b][k] == la);
        if (a != b && adj) atomicOr(&cm[a], 1u << b);
    }
    __syncthreads();

    if (tid < S) wsMask[n * S + tid] = cm[tid];
    if (tid >= 32 && tid < 32 + T * MN) {  // Mp[n,c] = xsq - 2*(x[n].F2f[c])
        int c = tid - 32;
        const float4* fr = (const float4*)(F2 + (size_t)c * D);
        const float4* xr = (const float4*)(x + (size_t)n * D);
        float dotv = 0.f;
        #pragma unroll 8
        for (int d4 = 0; d4 < D / 4; ++d4) {
            float4 f = fr[d4], xv = xr[d4];
            dotv += f.x*xv.x + f.y*xv.y + f.z*xv.z + f.w*xv.w;
        }
        wsMp[n * (T * MN) + c] = xsq_s - 2.f * dotv;
    }
}

// ---------------- Main: one wave = TWO (node, template) OT problems ----------------
// R16 structure (validated: 109.5 µs): lanes 0-31 = problem A, 32-63 = B; rows
// s = 2r+ql per lane, r=0..8 (pad at ql=1,r=8); bfly16-only column reduce; pad
// gate AFTER the Kt*ub product (R12 NaN discipline); rm2 parked in LDS.
// R17 single-variable change: WPB 8->4. With 4 waves/block each block puts
// exactly ONE wave per SIMD, so co-resident waves on a SIMD belong to blocks
// with different start times — their (identical-code) dependency-chain stalls
// desynchronize and fill each other's issue bubbles. Also 2x blocks (6250) for
// finer CU filling. PPW=4 was considered and rejected by arithmetic: rowsum16
// DPP already serves all 4 quads per instruction, so per-problem cost is
// layout-invariant (~6% pad savings vs 8->6 waves/SIMD occupancy loss).
// __launch_bounds__: block size ONLY (rounds 2-3: min-waves hint => spills).
__global__ __launch_bounds__(BLOCK) void ltfgw_wave(
    const int*      __restrict__ edge,     // [2, N*DEG]
    const float*    __restrict__ tmpl,     // [T, MN, MN]
    const float*    __restrict__ q0,       // [T, MN]
    const float*    __restrict__ alpha0,   // [1]
    const float*    __restrict__ wsMp,     // [N, 100]
    const unsigned* __restrict__ wsMask,   // [N, 17]
    const float*    __restrict__ wsSqF2,   // [100]
    float*          __restrict__ out)      // [N, T]
{
    const int tid  = threadIdx.x;
    const int w    = tid >> 6;
    const int lane = tid & 63;
    const int half = lane >> 5;              // which problem in the wave
    const int q    = lane >> 4;              // global quad 0..3
    const int ql   = q & 1;                  // quad within problem
    const int m    = lane & 15;
    const bool act = (m < MN);
    const int mc   = act ? m : (MN - 1);
    const bool pad8 = (ql == 1);             // slot r=8 is a pad on ql==1
    const int gid  = (blockIdx.x * WPB + w) * PPW + half;
    const int n    = gid / T;
    const int t    = gid - n * T;

    __shared__ __align__(16) float C2l[WPB][PPW][MN][17]; // per-problem C2
    __shared__ __align__(16) float GL [WPB][PPW][19][16]; // 0-16 G rows;17 colG;18 dump
    __shared__ __align__(16) float QL [WPB][PPW][16];     // q-weights (tail 0)
    __shared__               float RM [WPB][PPW][20];     // rm2 per row (epilogue)

    const int* dst = edge + NN * DEG;

    // q = softmax(q0[t]) via DPP row reduction (quads of a problem share t)
    float vq = q0[t * MN + mc];
    float zq = act ? vq : NEG;
    float mq = rowmax16(zq);
    float sq = rowsum16(__expf(zq - mq));     // inactive: exp(NEG-mq)=0
    const float qm = __expf(vq - (mq + __logf(sq)));   // valid on act lanes
    if (ql == 0) QL[w][half][m] = act ? qm : 0.f;      // per-problem q vector
    // C2 = softmax(tmpl, axis=1): active lane m of quad ql==0 does column m
    if (act && ql == 0) {
        float v[MN]; float cmx = NEG;
        #pragma unroll
        for (int i = 0; i < MN; ++i) { v[i] = tmpl[t * MN * MN + i * MN + m]; cmx = fmaxf(cmx, v[i]); }
        float ssum = 0.f;
        #pragma unroll
        for (int i = 0; i < MN; ++i) { v[i] = __expf(v[i] - cmx); ssum += v[i]; }
        float inv = fast_rcp(ssum);
        #pragma unroll
        for (int i = 0; i < MN; ++i) C2l[w][half][i][m] = v[i] * inv;
    }

    // per-row gathers (L1/L2-resident ws): rows s = 2r+ql, clamp 16 (pad)
    unsigned msk[RS]; float Mp[RS];
    const int cidx = t * MN + mc;
    #pragma unroll
    for (int r = 0; r < RS; ++r) {
        int s   = 2 * r + ql; s = (s > 16) ? 16 : s;
        int lr  = (s == 0) ? n : dst[n * DEG + s - 1];
        msk[r]  = wsMask[n * S + s];
        Mp[r]   = wsMp[lr * (T * MN) + cidx];
    }
    if (pad8) msk[8] = 0u;                    // pad slot contributes nothing
    const float sqf2c = wsSqF2[cidx];

    // C2 row mc in registers (same-wave LDS RAW ordered by compiler lgkmcnt)
    float crReg[MN];
    #pragma unroll
    for (int k = 0; k < MN; ++k) crReg[k] = C2l[w][half][mc][k];

    // hC2 = sum_k C2[mc][k]^2 q[k]; qC2m = sum_k C2[mc][k] q[k]
    float hC2 = 0.f, qC2m = 0.f;
    {
        float ql_[MN];
        #pragma unroll
        for (int k = 0; k < MN; ++k) ql_[k] = QL[w][half][k];
        #pragma unroll
        for (int k = 0; k < MN; ++k) {
            float cq = crReg[k] * ql_[k];
            qC2m += cq;
            hC2  = fmaf(crReg[k], cq, hC2);
        }
    }

    const float alpha = fast_rcp(1.f + __expf(-alpha0[0]));
    const float oma   = 1.f - alpha;
    const float p_    = 1.f / (float)S;
    const float fa42  = 40.f * alpha * LOG2E; // log2K = lkP2 + fa42*tens
    const float qop   = qm * (float)S;        // q/p for folded v-update
    const unsigned exm = act ? 0x1FFFEu : 0u; // extras mask (skip bit 0; gate act)

    // lkP2b = log2-domain linear part, pre-shifted by hoisted row stabilizer.
    // NEG on inactive lanes AND the pad slot => Kt = 0 with no per-outer mask.
    // rm2 parked in LDS (read only in the epilogue; quad-uniform broadcast).
    float lkP2b[RS];
    {
        const float nl2e10 = -10.f * LOG2E;
        #pragma unroll
        for (int r = 0; r < RS; ++r) {
            int s = 2 * r + ql; s = (s > 16) ? 16 : s;
            float M_  = Mp[r] + sqf2c;             // xsq + sqf2 - 2*dot
            float cC  = (float)__popc(msk[r]) * p_ + hC2;
            float lk2 = nl2e10 * (oma * M_ + 2.f * alpha * cC);
            float rm2 = rowmax16(act ? lk2 : NEG) + 14.4f;  // overflow headroom
            bool vld  = !(pad8 && r == 8);
            lkP2b[r]  = (act && vld) ? (lk2 - rm2) : NEG;
            if (m == 0 && vld) RM[w][half][s] = rm2;
        }
    }

    // outer 0 analytic: G0 = p q^T => tens0[r] = p * qC2m * popc(msk[r])
    float tens[RS], Kt[RS], ub[RS], v_, G[RS];
    {
        float pq = p_ * qC2m;
        #pragma unroll
        for (int r = 0; r < RS; ++r) tens[r] = pq * (float)__popc(msk[r]);
    }

    for (int o = 1; o <= NOUT; ++o) {
        // K~ = exp2(lkP2b + fa42*tens): 0 on inactive lanes and pad slot
        #pragma unroll
        for (int r = 0; r < RS; ++r)
            Kt[r] = fast_exp2(fmaf(fa42, tens[r], lkP2b[r]));

        // folded exp-domain Sinkhorn: û = rcp(K~ v); v = (Sq)*rcp(K~^T û)
        // iter 0 peeled (v == 1). Column reduce = bfly16 only (2 quads).
        // Pad slot: ub[8]=inf, a8=0*inf=NaN — gated AFTER the product (R12!).
        #pragma unroll
        for (int r = 0; r < RS; ++r) ub[r] = fast_rcp(rowsum16(Kt[r]));
        {
            float a8  = Kt[8] * ub[8];
            float a8g = pad8 ? 0.f : a8;
            float cs  = (((Kt[0]*ub[0] + Kt[1]*ub[1]) + (Kt[2]*ub[2] + Kt[3]*ub[3]))
                       + ((Kt[4]*ub[4] + Kt[5]*ub[5]) + (Kt[6]*ub[6] + Kt[7]*ub[7])))
                       + (a8g + TINY);
            cs = bfly16(cs);
            v_ = qop * fast_rcp(cs);
        }
        #pragma unroll
        for (int it = 1; it < NSK; ++it) {
            #pragma unroll
            for (int r = 0; r < RS; ++r)
                ub[r] = fast_rcp(rowsum16(Kt[r] * v_));
            float a8  = Kt[8] * ub[8];
            float a8g = pad8 ? 0.f : a8;
            float cs  = (((Kt[0]*ub[0] + Kt[1]*ub[1]) + (Kt[2]*ub[2] + Kt[3]*ub[3]))
                       + ((Kt[4]*ub[4] + Kt[5]*ub[5]) + (Kt[6]*ub[6] + Kt[7]*ub[7])))
                       + (a8g + TINY);
            cs = bfly16(cs);
            v_ = qop * fast_rcp(cs);
        }
        float pv = p_ * v_;
        #pragma unroll
        for (int r = 0; r < RS; ++r) G[r] = Kt[r] * ub[r] * pv;  // G[8]=NaN on pad

        // ---- tens = C1*(G*C2^T), star-decomposed; dots via LDS ----
        #pragma unroll
        for (int r = 0; r < 8; ++r) GL[w][half][2*r + ql][m] = G[r];  // rows 0..15
        GL[w][half][pad8 ? 18 : 16][m] = G[8];                        // row 16 / dump
        // colG[k] = sum over the problem's 17 rows (pad gated; NaN discarded)
        float cg = (((G[0]+G[1]) + (G[2]+G[3])) + ((G[4]+G[5]) + (G[6]+G[7])))
                 + (pad8 ? 0.f : G[8]);
        cg = bfly16(cg);
        if (ql == 0) GL[w][half][17][m] = cg;
        // Fm[m] = sum_k colG[k]*C2[mc][k]; H0[m] = sum_k G[0][k]*C2[mc][k]
        float Fm = dot10(&GL[w][half][17][0], crReg);
        float H0 = dot10(&GL[w][half][0][0],  crReg);
        // tens: row 0 (ql=0,r=0) = Fm - H0 (all bits 1..16 set);
        // rows s>=1 = H0 + rare extras (10-term LDS dots, ~0.1 bits/row).
        #pragma unroll
        for (int r = 0; r < RS; ++r) {
            unsigned ex = msk[r] & exm;              // extras: bits 1..16
            if (r == 0) ex = (ql == 0) ? 0u : ex;    // row 0 handled via Fm
            float tn = H0;                           // bit 0 always set for s>=1
            while (ex) {
                int j = __builtin_ctz(ex);
                ex &= ex - 1u;
                tn += dot10(&GL[w][half][j][0], crReg);
            }
            tens[r] = tn;
        }
        if (ql == 0) tens[0] = Fm - H0;
    }

    // dist = sum G * ((1-a)M + a*constC - 2a*tens); lk2 = lkP2b + rm2 (log2)
    float val = 0.f;
    #pragma unroll
    for (int r = 0; r < RS; ++r) {
        int s = 2 * r + ql; s = (s > 16) ? 16 : s;
        float cC   = (float)__popc(msk[r]) * p_ + hC2;
        float lk2r = lkP2b[r] + RM[w][half][s];
        float integ = -(0.1f * LN2) * lk2r - alpha * cC - 2.f * alpha * tens[r];
        bool valid = act && !(pad8 && r == 8);
        val += valid ? G[r] * integ : 0.f;
    }
    val = rowsum16(val);
    val = bfly16(val);
    if ((lane & 31) == 0) out[gid] = val;
}

extern "C" void kernel_launch(void* const* d_in, const int* in_sizes, int n_in,
                              void* d_out, int out_size, void* d_ws, size_t ws_size,
                              hipStream_t stream) {
    const float* x      = (const float*)d_in[0];
    const int*   edge   = (const int*)  d_in[1];
    const float* tmpl   = (const float*)d_in[2];
    const float* F2     = (const float*)d_in[3];
    const float* q0     = (const float*)d_in[4];
    const float* alpha0 = (const float*)d_in[5];
    float*       out    = (float*)d_out;

    // ws layout: Mp [N*100] f32 | masks [N*17] u32 | sqF2 [100] f32  (~2.34 MB)
    float*    wsMp    = (float*)d_ws;
    unsigned* wsMask  = (unsigned*)((char*)d_ws + (size_t)NN * T * MN * 4);
    float*    wsSqF2  = (float*)((char*)d_ws + (size_t)NN * T * MN * 4 + (size_t)NN * S * 4);

    hipLaunchKernelGGL(ltfgw_pre, dim3(NN + 1), dim3(320), 0, stream,
                       x, edge, F2, wsMp, wsMask, wsSqF2);
    hipLaunchKernelGGL(ltfgw_wave, dim3(NN * T / (WPB * PPW)), dim3(BLOCK), 0, stream,
                       edge, tmpl, q0, alpha0, wsMp, wsMask, wsSqF2, out);
}

// Round 10
// 194.185 us; speedup vs baseline: 1.1758x; 1.0070x over previous
//
#include <hip/hip_runtime.h>
#include <math.h>

#define NN   5000
#define DEG  16
#define S    17
#define T    10
#define MN   10
#define D    128
#define NOUT 3
#define NSK  5

#define WPB   4            // waves per block (R17: 1 wave/SIMD/block — desync)
#define PPW   2            // problems per wave (lanes 0-31 / 32-63)
#define BLOCK (WPB * 64)
#define RS    9            // row slots per lane: ceil(17 rows / 2 quads)
#define NEG   -3.0e38f
#define LOG2E 1.44269504088896f
#define LN2   0.69314718055995f
#define TINY  1e-30f       // cs floor: keeps inactive-column v_ finite (0*inf=NaN!)

typedef unsigned uint2v __attribute__((ext_vector_type(2)));

__device__ __forceinline__ float fast_rcp(float x) { return __builtin_amdgcn_rcpf(x); }

#if __has_builtin(__builtin_amdgcn_exp2f)
__device__ __forceinline__ float fast_exp2(float x) { return __builtin_amdgcn_exp2f(x); }
#else
__device__ __forceinline__ float fast_exp2(float x) { return __expf(x * LN2); }
#endif

// DPP row_ror:k — pure-VALU cross-lane within each 16-lane row (fused to
// v_add/max_f32_dpp by GCNDPPCombine).
template <int CTRL>
__device__ __forceinline__ float dpp_movf(float v) {
    return __int_as_float(__builtin_amdgcn_update_dpp(
        0, __float_as_int(v), CTRL, 0xF, 0xF, true));
}
__device__ __forceinline__ float rowsum16(float v) {
    v += dpp_movf<0x121>(v);
    v += dpp_movf<0x122>(v);
    v += dpp_movf<0x124>(v);
    v += dpp_movf<0x128>(v);
    return v;
}
__device__ __forceinline__ float rowmax16(float v) {
    v = fmaxf(v, dpp_movf<0x121>(v));
    v = fmaxf(v, dpp_movf<0x122>(v));
    v = fmaxf(v, dpp_movf<0x124>(v));
    v = fmaxf(v, dpp_movf<0x128>(v));
    return v;
}

// gfx950 permlane16-swap butterfly: v + v[lane^16] in pure VALU.
__device__ __forceinline__ float bfly16(float v) {
#if __has_builtin(__builtin_amdgcn_permlane16_swap)
    uint2v r = __builtin_amdgcn_permlane16_swap(__float_as_uint(v), __float_as_uint(v),
                                                false, false);
    return __uint_as_float(r[0]) + __uint_as_float(r[1]);
#else
    return v + __int_as_float(__builtin_amdgcn_ds_swizzle(__float_as_int(v), 0x401F));
#endif
}

// 10-term dot of an LDS row (16B-aligned, 16-float stride) with a register
// array: 3 vector ds_reads (LDS pipe, co-issues with VALU) + 14 VALU, depth ~3.
__device__ __forceinline__ float dot10(const float* __restrict__ row,
                                       const float* __restrict__ cr) {
    float4 a = *(const float4*)(row);
    float4 b = *(const float4*)(row + 4);
    float2 c = *(const float2*)(row + 8);
    float e0 = fmaf(cr[1], a.y, cr[0] * a.x);
    float e1 = fmaf(cr[3], a.w, cr[2] * a.z);
    float e2 = fmaf(cr[5], b.y, cr[4] * b.x);
    float e3 = fmaf(cr[7], b.w, cr[6] * b.z);
    float e4 = fmaf(cr[9], c.y, cr[8] * c.x);
    return ((e0 + e1) + (e2 + e3)) + e4;
}

// ---------------- Pre-kernel: masks + xsq (+ block NN: sqF2 & F2 transpose) --------
// R18: the Mp phase is REMOVED from this kernel. Its F2 reads were the pre
// bottleneck: lane c reading F2 rows 512B apart => every float4 load fans out
// to 64 cache lines (~2048 L1/L2 transactions/block x 5000 blocks). Mp moves
// to ltfgw_mp (coalesced via F2T). Here: masks + xsq->wsXsq; block NN also
// writes F2T[d][c] = F2[c][d] and sqF2.
__global__ __launch_bounds__(320) void ltfgw_pre(
    const float* __restrict__ x,        // [N, D]
    const int*   __restrict__ edge,     // [2, N*DEG]
    const float* __restrict__ F2,       // [T, MN, D] == [100, D] flat
    unsigned*    __restrict__ wsMask,   // [N, 17]   adjacency bitmasks
    float*       __restrict__ wsSqF2,   // [100]
    float*       __restrict__ wsXsq,    // [N]       ||x[n]||^2
    float*       __restrict__ wsF2T)    // [D, 100]  transposed features
{
    const int n   = blockIdx.x;
    const int tid = threadIdx.x;
    const int* dst = edge + NN * DEG;

    if (n == NN) {                       // sqF2[c] = ||F2f[c]||^2 ; F2T
        if (tid < T * MN) {
            const float4* fr = (const float4*)(F2 + (size_t)tid * D);
            float acc = 0.f;
            #pragma unroll 8
            for (int i = 0; i < D / 4; ++i) {
                float4 f = fr[i];
                acc += f.x*f.x + f.y*f.y + f.z*f.z + f.w*f.w;
            }
            wsSqF2[tid] = acc;
        }
        for (int e = tid; e < D * T * MN; e += 320) {   // F2T[d*100+c]=F2[c*128+d]
            int d = e / (T * MN);
            int c = e - d * (T * MN);
            wsF2T[e] = F2[c * D + d];
        }
        return;
    }

    __shared__ int      loc[S];
    __shared__ int      neigh[S][DEG];
    __shared__ unsigned cm[S];

    if (tid < S) { loc[tid] = (tid == 0) ? n : dst[n * DEG + tid - 1]; cm[tid] = 0u; }
    __syncthreads();

    if (tid < S * DEG) neigh[tid >> 4][tid & 15] = dst[loc[tid >> 4] * DEG + (tid & 15)];
    if (tid < 64) {                      // xsq[n] via wave-0 DPP reduce -> global
        float v0 = x[(size_t)n * D + tid];
        float v1 = x[(size_t)n * D + 64 + tid];
        float pp = v0 * v0 + v1 * v1;
        pp = rowsum16(pp);
        pp += __shfl_xor(pp, 16, 64);
        pp += __shfl_xor(pp, 32, 64);
        if (tid == 0) wsXsq[n] = pp;
    }
    __syncthreads();

    if (tid < S * S) {
        int a = tid / S, b = tid % S;
        int la = loc[a], lb = loc[b];
        bool adj = false;
        #pragma unroll
        for (int k = 0; k < DEG; ++k) adj = adj | (neigh[a][k] == lb) | (neigh[b][k] == la);
        if (a != b && adj) atomicOr(&cm[a], 1u << b);
    }
    __syncthreads();

    if (tid < S) wsMask[n * S + tid] = cm[tid];
}

// ---------------- Mp kernel: the 5000x128 @ 128x100 mini-GEMM, coalesced ----------
// Thread = 2 adjacent (n,c) outputs (o2 even => c even, pair never crosses n).
// F2T reads: lanes' c contiguous => coalesced float2; x reads near-broadcast
// (50 threads share a row, L1 hit). Mp[n,c] = xsq[n] - 2*dot. ~64M MACs total
// = a few µs at full chip, vs the old fan-out implementation inside pre.
__global__ __launch_bounds__(256) void ltfgw_mp(
    const float* __restrict__ x,        // [N, D]
    const float* __restrict__ wsF2T,    // [D, 100]
    const float* __restrict__ wsXsq,    // [N]
    float*       __restrict__ wsMp)     // [N, 100]
{
    int o2 = (blockIdx.x * 256 + threadIdx.x) * 2;
    if (o2 >= NN * T * MN) return;
    int n = o2 / (T * MN);
    int c = o2 - n * (T * MN);
    const float* xr = x + (size_t)n * D;
    float ax = 0.f, ay = 0.f;
    #pragma unroll 8
    for (int d4 = 0; d4 < D / 4; ++d4) {
        float4 xv = *(const float4*)(xr + d4 * 4);
        float2 f0 = *(const float2*)(wsF2T + (d4 * 4 + 0) * (T * MN) + c);
        float2 f1 = *(const float2*)(wsF2T + (d4 * 4 + 1) * (T * MN) + c);
        float2 f2 = *(const float2*)(wsF2T + (d4 * 4 + 2) * (T * MN) + c);
        float2 f3 = *(const float2*)(wsF2T + (d4 * 4 + 3) * (T * MN) + c);
        ax = fmaf(xv.x, f0.x, ax); ay = fmaf(xv.x, f0.y, ay);
        ax = fmaf(xv.y, f1.x, ax); ay = fmaf(xv.y, f1.y, ay);
        ax = fmaf(xv.z, f2.x, ax); ay = fmaf(xv.z, f2.y, ay);
        ax = fmaf(xv.w, f3.x, ax); ay = fmaf(xv.w, f3.y, ay);
    }
    float xs = wsXsq[n];
    float2 r;
    r.x = xs - 2.f * ax;
    r.y = xs - 2.f * ay;
    *(float2*)(wsMp + o2) = r;
}

// ---------------- Main: one wave = TWO (node, template) OT problems ----------------
// UNCHANGED from R17 (validated: 104 µs). Lanes 0-31 = problem A, 32-63 = B;
// rows s = 2r+ql per lane, r=0..8 (pad at ql=1,r=8); bfly16-only column
// reduce; pad gate AFTER the Kt*ub product (R12 NaN discipline); rm2 in LDS.
// __launch_bounds__: block size ONLY (rounds 2-3: min-waves hint => spills).
__global__ __launch_bounds__(BLOCK) void ltfgw_wave(
    const int*      __restrict__ edge,     // [2, N*DEG]
    const float*    __restrict__ tmpl,     // [T, MN, MN]
    const float*    __restrict__ q0,       // [T, MN]
    const float*    __restrict__ alpha0,   // [1]
    const float*    __restrict__ wsMp,     // [N, 100]
    const unsigned* __restrict__ wsMask,   // [N, 17]
    const float*    __restrict__ wsSqF2,   // [100]
    float*          __restrict__ out)      // [N, T]
{
    const int tid  = threadIdx.x;
    const int w    = tid >> 6;
    const int lane = tid & 63;
    const int half = lane >> 5;              // which problem in the wave
    const int q    = lane >> 4;              // global quad 0..3
    const int ql   = q & 1;                  // quad within problem
    const int m    = lane & 15;
    const bool act = (m < MN);
    const int mc   = act ? m : (MN - 1);
    const bool pad8 = (ql == 1);             // slot r=8 is a pad on ql==1
    const int gid  = (blockIdx.x * WPB + w) * PPW + half;
    const int n    = gid / T;
    const int t    = gid - n * T;

    __shared__ __align__(16) float C2l[WPB][PPW][MN][17]; // per-problem C2
    __shared__ __align__(16) float GL [WPB][PPW][19][16]; // 0-16 G rows;17 colG;18 dump
    __shared__ __align__(16) float QL [WPB][PPW][16];     // q-weights (tail 0)
    __shared__               float RM [WPB][PPW][20];     // rm2 per row (epilogue)

    const int* dst = edge + NN * DEG;

    // q = softmax(q0[t]) via DPP row reduction (quads of a problem share t)
    float vq = q0[t * MN + mc];
    float zq = act ? vq : NEG;
    float mq = rowmax16(zq);
    float sq = rowsum16(__expf(zq - mq));     // inactive: exp(NEG-mq)=0
    const float qm = __expf(vq - (mq + __logf(sq)));   // valid on act lanes
    if (ql == 0) QL[w][half][m] = act ? qm : 0.f;      // per-problem q vector
    // C2 = softmax(tmpl, axis=1): active lane m of quad ql==0 does column m
    if (act && ql == 0) {
        float v[MN]; float cmx = NEG;
        #pragma unroll
        for (int i = 0; i < MN; ++i) { v[i] = tmpl[t * MN * MN + i * MN + m]; cmx = fmaxf(cmx, v[i]); }
        float ssum = 0.f;
        #pragma unroll
        for (int i = 0; i < MN; ++i) { v[i] = __expf(v[i] - cmx); ssum += v[i]; }
        float inv = fast_rcp(ssum);
        #pragma unroll
        for (int i = 0; i < MN; ++i) C2l[w][half][i][m] = v[i] * inv;
    }

    // per-row gathers (L1/L2-resident ws): rows s = 2r+ql, clamp 16 (pad)
    unsigned msk[RS]; float Mp[RS];
    const int cidx = t * MN + mc;
    #pragma unroll
    for (int r = 0; r < RS; ++r) {
        int s   = 2 * r + ql; s = (s > 16) ? 16 : s;
        int lr  = (s == 0) ? n : dst[n * DEG + s - 1];
        msk[r]  = wsMask[n * S + s];
        Mp[r]   = wsMp[lr * (T * MN) + cidx];
    }
    if (pad8) msk[8] = 0u;                    // pad slot contributes nothing
    const float sqf2c = wsSqF2[cidx];

    // C2 row mc in registers (same-wave LDS RAW ordered by compiler lgkmcnt)
    float crReg[MN];
    #pragma unroll
    for (int k = 0; k < MN; ++k) crReg[k] = C2l[w][half][mc][k];

    // hC2 = sum_k C2[mc][k]^2 q[k]; qC2m = sum_k C2[mc][k] q[k]
    float hC2 = 0.f, qC2m = 0.f;
    {
        float ql_[MN];
        #pragma unroll
        for (int k = 0; k < MN; ++k) ql_[k] = QL[w][half][k];
        #pragma unroll
        for (int k = 0; k < MN; ++k) {
            float cq = crReg[k] * ql_[k];
            qC2m += cq;
            hC2  = fmaf(crReg[k], cq, hC2);
        }
    }

    const float alpha = fast_rcp(1.f + __expf(-alpha0[0]));
    const float oma   = 1.f - alpha;
    const float p_    = 1.f / (float)S;
    const float fa42  = 40.f * alpha * LOG2E; // log2K = lkP2 + fa42*tens
    const float qop   = qm * (float)S;        // q/p for folded v-update
    const unsigned exm = act ? 0x1FFFEu : 0u; // extras mask (skip bit 0; gate act)

    // lkP2b = log2-domain linear part, pre-shifted by hoisted row stabilizer.
    // NEG on inactive lanes AND the pad slot => Kt = 0 with no per-outer mask.
    // rm2 parked in LDS (read only in the epilogue; quad-uniform broadcast).
    float lkP2b[RS];
    {
        const float nl2e10 = -10.f * LOG2E;
        #pragma unroll
        for (int r = 0; r < RS; ++r) {
            int s = 2 * r + ql; s = (s > 16) ? 16 : s;
            float M_  = Mp[r] + sqf2c;             // xsq + sqf2 - 2*dot
            float cC  = (float)__popc(msk[r]) * p_ + hC2;
            float lk2 = nl2e10 * (oma * M_ + 2.f * alpha * cC);
            float rm2 = rowmax16(act ? lk2 : NEG) + 14.4f;  // overflow headroom
            bool vld  = !(pad8 && r == 8);
            lkP2b[r]  = (act && vld) ? (lk2 - rm2) : NEG;
            if (m == 0 && vld) RM[w][half][s] = rm2;
        }
    }

    // outer 0 analytic: G0 = p q^T => tens0[r] = p * qC2m * popc(msk[r])
    float tens[RS], Kt[RS], ub[RS], v_, G[RS];
    {
        float pq = p_ * qC2m;
        #pragma unroll
        for (int r = 0; r < RS; ++r) tens[r] = pq * (float)__popc(msk[r]);
    }

    for (int o = 1; o <= NOUT; ++o) {
        // K~ = exp2(lkP2b + fa42*tens): 0 on inactive lanes and pad slot
        #pragma unroll
        for (int r = 0; r < RS; ++r)
            Kt[r] = fast_exp2(fmaf(fa42, tens[r], lkP2b[r]));

        // folded exp-domain Sinkhorn: û = rcp(K~ v); v = (Sq)*rcp(K~^T û)
        // iter 0 peeled (v == 1). Column reduce = bfly16 only (2 quads).
        // Pad slot: ub[8]=inf, a8=0*inf=NaN — gated AFTER the product (R12!).
        #pragma unroll
        for (int r = 0; r < RS; ++r) ub[r] = fast_rcp(rowsum16(Kt[r]));
        {
            float a8  = Kt[8] * ub[8];
            float a8g = pad8 ? 0.f : a8;
            float cs  = (((Kt[0]*ub[0] + Kt[1]*ub[1]) + (Kt[2]*ub[2] + Kt[3]*ub[3]))
                       + ((Kt[4]*ub[4] + Kt[5]*ub[5]) + (Kt[6]*ub[6] + Kt[7]*ub[7])))
                       + (a8g + TINY);
            cs = bfly16(cs);
            v_ = qop * fast_rcp(cs);
        }
        #pragma unroll
        for (int it = 1; it < NSK; ++it) {
            #pragma unroll
            for (int r = 0; r < RS; ++r)
                ub[r] = fast_rcp(rowsum16(Kt[r] * v_));
            float a8  = Kt[8] * ub[8];
            float a8g = pad8 ? 0.f : a8;
            float cs  = (((Kt[0]*ub[0] + Kt[1]*ub[1]) + (Kt[2]*ub[2] + Kt[3]*ub[3]))
                       + ((Kt[4]*ub[4] + Kt[5]*ub[5]) + (Kt[6]*ub[6] + Kt[7]*ub[7])))
                       + (a8g + TINY);
            cs = bfly16(cs);
            v_ = qop * fast_rcp(cs);
        }
        float pv = p_ * v_;
        #pragma unroll
        for (int r = 0; r < RS; ++r) G[r] = Kt[r] * ub[r] * pv;  // G[8]=NaN on pad

        // ---- tens = C1*(G*C2^T), star-decomposed; dots via LDS ----
        #pragma unroll
        for (int r = 0; r < 8; ++r) GL[w][half][2*r + ql][m] = G[r];  // rows 0..15
        GL[w][half][pad8 ? 18 : 16][m] = G[8];                        // row 16 / dump
        // colG[k] = sum over the problem's 17 rows (pad gated; NaN discarded)
        float cg = (((G[0]+G[1]) + (G[2]+G[3])) + ((G[4]+G[5]) + (G[6]+G[7])))
                 + (pad8 ? 0.f : G[8]);
        cg = bfly16(cg);
        if (ql == 0) GL[w][half][17][m] = cg;
        // Fm[m] = sum_k colG[k]*C2[mc][k]; H0[m] = sum_k G[0][k]*C2[mc][k]
        float Fm = dot10(&GL[w][half][17][0], crReg);
        float H0 = dot10(&GL[w][half][0][0],  crReg);
        // tens: row 0 (ql=0,r=0) = Fm - H0 (all bits 1..16 set);
        // rows s>=1 = H0 + rare extras (10-term LDS dots, ~0.1 bits/row).
        #pragma unroll
        for (int r = 0; r < RS; ++r) {
            unsigned ex = msk[r] & exm;              // extras: bits 1..16
            if (r == 0) ex = (ql == 0) ? 0u : ex;    // row 0 handled via Fm
            float tn = H0;                           // bit 0 always set for s>=1
            while (ex) {
                int j = __builtin_ctz(ex);
                ex &= ex - 1u;
                tn += dot10(&GL[w][half][j][0], crReg);
            }
            tens[r] = tn;
        }
        if (ql == 0) tens[0] = Fm - H0;
    }

    // dist = sum G * ((1-a)M + a*constC - 2a*tens); lk2 = lkP2b + rm2 (log2)
    float val = 0.f;
    #pragma unroll
    for (int r = 0; r < RS; ++r) {
        int s = 2 * r + ql; s = (s > 16) ? 16 : s;
        float cC   = (float)__popc(msk[r]) * p_ + hC2;
        float lk2r = lkP2b[r] + RM[w][half][s];
        float integ = -(0.1f * LN2) * lk2r - alpha * cC - 2.f * alpha * tens[r];
        bool valid = act && !(pad8 && r == 8);
        val += valid ? G[r] * integ : 0.f;
    }
    val = rowsum16(val);
    val = bfly16(val);
    if ((lane & 31) == 0) out[gid] = val;
}

extern "C" void kernel_launch(void* const* d_in, const int* in_sizes, int n_in,
                              void* d_out, int out_size, void* d_ws, size_t ws_size,
                              hipStream_t stream) {
    const float* x      = (const float*)d_in[0];
    const int*   edge   = (const int*)  d_in[1];
    const float* tmpl   = (const float*)d_in[2];
    const float* F2     = (const float*)d_in[3];
    const float* q0     = (const float*)d_in[4];
    const float* alpha0 = (const float*)d_in[5];
    float*       out    = (float*)d_out;

    // ws layout (bytes):
    //   Mp    [N*100] f32   @ 0          (2,000,000)
    //   Mask  [N*17]  u32   @ 2,000,000  (  340,000)
    //   sqF2  [100]   f32   @ 2,340,000  (      400)
    //   Xsq   [N]     f32   @ 2,340,400  (   20,000)
    //   F2T   [D*100] f32   @ 2,360,400  (   51,200)  (8B-aligned for float2)
    char* wsb = (char*)d_ws;
    float*    wsMp    = (float*)wsb;
    unsigned* wsMask  = (unsigned*)(wsb + 2000000);
    float*    wsSqF2  = (float*)(wsb + 2340000);
    float*    wsXsq   = (float*)(wsb + 2340400);
    float*    wsF2T   = (float*)(wsb + 2360400);

    hipLaunchKernelGGL(ltfgw_pre, dim3(NN + 1), dim3(320), 0, stream,
                       x, edge, F2, wsMask, wsSqF2, wsXsq, wsF2T);
    hipLaunchKernelGGL(ltfgw_mp, dim3((NN * T * MN / 2 + 255) / 256), dim3(256), 0, stream,
                       x, wsF2T, wsXsq, wsMp);
    hipLaunchKernelGGL(ltfgw_wave, dim3(NN * T / (WPB * PPW)), dim3(BLOCK), 0, stream,
                       edge, tmpl, q0, alpha0, wsMp, wsMask, wsSqF2, out);
}